// Round 8
// baseline (89.556 us; speedup 1.0000x reference)
//
#include <hip/hip_runtime.h>

typedef __attribute__((ext_vector_type(8))) short bf16x8;
typedef __attribute__((ext_vector_type(4))) float f32x4;

#define MSP   262144          // 64*64*64 spatial per (b, ch)
#define BATCH 4
#define NT    8               // 32-pos tiles per wave
#define NBLK  256             // blocks/batch: 256 * 4 waves * 8 tiles * 32 pos = MSP

#define CSF2  264             // LDS chunk stride (floats): 8 rows x 32 + 8 pad
#define WT2   (4 * CSF2)      // floats per wave tile buffer (1056 = 4.2 KB)

// ws layout (float offsets): P[4][1024] then CS[4][1024]
#define OFF_P  0
#define OFF_CS 4096

// async global->LDS, 16B per lane; LDS dest wave-uniform, global src per-lane
#define GLDS16(gsrc, ldst)                                               \
  __builtin_amdgcn_global_load_lds(                                      \
      (const __attribute__((address_space(1))) unsigned int*)(gsrc),     \
      (__attribute__((address_space(3))) unsigned int*)(ldst), 16, 0, 0)

__device__ __forceinline__ unsigned short f2bf(float f) {  // RNE
  unsigned int u = __float_as_uint(f);
  u += 0x7fffu + ((u >> 16) & 1u);
  return (unsigned short)(u >> 16);
}
// hi = RNE bf16, lo = trunc bf16 of residual (pair captures f to ~2^-17 rel)
__device__ __forceinline__ void split2(float f, short* hi, short* lo) {
  unsigned int u = __float_as_uint(f);
  unsigned int uh = u + (0x7fffu + ((u >> 16) & 1u));
  *hi = (short)(uh >> 16);
  const float r = f - __uint_as_float(uh & 0xffff0000u);
  *lo = (short)(__float_as_uint(r) >> 16);
}

#define MFMA(A, B, C) __builtin_amdgcn_mfma_f32_16x16x32_bf16(A, B, C, 0, 0, 0)

// k-hat mapping: reg r<4 -> ch = 4*lb+r, r>=4 -> 16+4*lb+(r-4).
// Used consistently for BOTH operands of every MFMA => any true HW k-order cancels.
//
// LDS tile layout (per wave): chunk c holds rows 8c..8c+7 (32 floats each),
// row rotated by 4*(row&7) floats at the GLOBAL SOURCE (GLDS16 dest stays linear):
//   elem(ch, col) at (ch>>3)*CSF2 + (ch&7)*32 + 4*(((col>>2) - (ch&7)) & 7) + (col&3)
// Frag ds_read_b32 lands 2-way bank-aliased (free); residual b128 stays contiguous
// (rotation moves whole 16B granules within the 128B row).

// Pass 1: wave-private dbuf 32-pos tiles, counted vmcnt, no loop barriers.
// Y = U*X (MFMA), P += X^T Y (MFMA), colsum fp32; atomic P/CS.
__global__ __launch_bounds__(256) void pass1_kernel(
    const float* __restrict__ x, const float* __restrict__ Wq,
    const float* __restrict__ Wk, float* __restrict__ ws) {
  __shared__ __align__(16) float XT[8 * WT2];   // 4 waves x 2 bufs x 1056 (33.8 KB)
  __shared__ float UL[1024];
  const int tid = threadIdx.x;
  const int w = tid >> 6, l = tid & 63, lm = tid & 15, lb = (tid >> 4) & 3;
  const int b = blockIdx.y;
  const size_t xbase = (size_t)b * 32 * MSP;
  const int wbase = (blockIdx.x * 4 + w) * (NT * 32);

  const int srow = l >> 3;                       // row within chunk (0..7)
  const int scol = (((l & 7) + srow) & 7) * 4;   // rotated source granule
  float* wbuf0 = XT + (w * 2 + 0) * WT2;
  float* wbuf1 = XT + (w * 2 + 1) * WT2;
  const float* csrc[4];
#pragma unroll
  for (int c = 0; c < 4; ++c)
    csrc[c] = x + xbase + (size_t)(c * 8 + srow) * MSP + scol;

  // issue tile0 (completes under U-prep below)
#pragma unroll
  for (int c = 0; c < 4; ++c)
    GLDS16(csrc[c] + wbase, wbuf0 + c * CSF2);

  // ---- per-block U prep, straight from global (L2-hot 8 KB) ----
  for (int k = tid; k < 1024; k += 256) {
    const int aa = k >> 5, bb = k & 31;
    float s = 0.f;
#pragma unroll
    for (int ch = 0; ch < 32; ++ch)
      s = fmaf(Wq[ch * 32 + aa], Wk[ch * 32 + bb], s);
    UL[k] = s;   // U[aa][bb]
  }
  __syncthreads();   // UL ready (also drains tile0 loads)

  bf16x8 uh0, ul0, uh1, ul1;
#pragma unroll
  for (int r = 0; r < 8; ++r) {
    const int kk = (r < 4) ? lb * 4 + r : 16 + lb * 4 + (r - 4);
    short h, lo;
    split2(UL[lm * 32 + kk], &h, &lo);        uh0[r] = h; ul0[r] = lo;
    split2(UL[(16 + lm) * 32 + kk], &h, &lo); uh1[r] = h; ul1[r] = lo;
  }

  int off0[8], off1[8];
#pragma unroll
  for (int r = 0; r < 8; ++r) {
    const int ch = (r < 4) ? lb * 4 + r : 16 + lb * 4 + (r - 4);
    const int base = (ch >> 3) * CSF2 + (ch & 7) * 32 + (lm & 3);
    const int g0 = ((lm >> 2) - (ch & 7)) & 7;
    off0[r] = base + g0 * 4;                 // element (ch, lm)
    off1[r] = base + ((g0 + 4) & 7) * 4;     // element (ch, 16+lm)
  }

  f32x4 p00 = {0, 0, 0, 0}, p01 = {0, 0, 0, 0}, p10 = {0, 0, 0, 0}, p11 = {0, 0, 0, 0};
  float cs0[8], cs1[8];
#pragma unroll
  for (int r = 0; r < 8; ++r) { cs0[r] = 0.f; cs1[r] = 0.f; }

#pragma unroll 1
  for (int t = 0; t < NT; ++t) {
    const float* XB = (t & 1) ? wbuf1 : wbuf0;
    float* XN = (t & 1) ? wbuf0 : wbuf1;
    if (t + 1 < NT) {
      const int posn = wbase + (t + 1) * 32;
#pragma unroll
      for (int c = 0; c < 4; ++c)
        GLDS16(csrc[c] + posn, XN + c * CSF2);
      asm volatile("s_waitcnt vmcnt(4)" ::: "memory");   // tile t ready
    } else {
      asm volatile("s_waitcnt vmcnt(0)" ::: "memory");
    }
    __builtin_amdgcn_sched_barrier(0);

    float xf0[8], xf1[8];
#pragma unroll
    for (int r = 0; r < 8; ++r) { xf0[r] = XB[off0[r]]; xf1[r] = XB[off1[r]]; }
    bf16x8 xh0, xl0, xh1, xl1;
#pragma unroll
    for (int r = 0; r < 8; ++r) {
      short h, lo;
      split2(xf0[r], &h, &lo); xh0[r] = h; xl0[r] = lo;
      split2(xf1[r], &h, &lo); xh1[r] = h; xl1[r] = lo;
      cs0[r] += xf0[r];  cs1[r] += xf1[r];
    }

    __builtin_amdgcn_s_setprio(1);
    // channel mix: Y[ch][pos]; hh + hl + lh
    f32x4 y00 = {0,0,0,0}, y01 = {0,0,0,0}, y10 = {0,0,0,0}, y11 = {0,0,0,0};
    y00 = MFMA(uh0, xh0, y00); y00 = MFMA(uh0, xl0, y00); y00 = MFMA(ul0, xh0, y00);
    y01 = MFMA(uh1, xh0, y01); y01 = MFMA(uh1, xl0, y01); y01 = MFMA(ul1, xh0, y01);
    y10 = MFMA(uh0, xh1, y10); y10 = MFMA(uh0, xl1, y10); y10 = MFMA(ul0, xh1, y10);
    y11 = MFMA(uh1, xh1, y11); y11 = MFMA(uh1, xl1, y11); y11 = MFMA(ul1, xh1, y11);

    // repack Y accs into k-hat B-frags + split
    bf16x8 yh0, yl0, yh1, yl1;
#pragma unroll
    for (int r = 0; r < 4; ++r) {
      short h, lo;
      split2(y00[r], &h, &lo); yh0[r] = h; yl0[r] = lo;
      split2(y10[r], &h, &lo); yh1[r] = h; yl1[r] = lo;
    }
#pragma unroll
    for (int r = 4; r < 8; ++r) {
      short h, lo;
      split2(y01[r - 4], &h, &lo); yh0[r] = h; yl0[r] = lo;
      split2(y11[r - 4], &h, &lo); yh1[r] = h; yl1[r] = lo;
    }

    // Gram: P[it][jt] += X^T Y; hh + hl + lh
    p00 = MFMA(xh0, yh0, p00); p00 = MFMA(xh0, yl0, p00); p00 = MFMA(xl0, yh0, p00);
    p01 = MFMA(xh0, yh1, p01); p01 = MFMA(xh0, yl1, p01); p01 = MFMA(xl0, yh1, p01);
    p10 = MFMA(xh1, yh0, p10); p10 = MFMA(xh1, yl0, p10); p10 = MFMA(xl1, yh0, p10);
    p11 = MFMA(xh1, yh1, p11); p11 = MFMA(xh1, yl1, p11); p11 = MFMA(xl1, yh1, p11);
    __builtin_amdgcn_s_setprio(0);
  }

  // block reduce (reuse XT as [4][1024] scratch)
  __syncthreads();
  float* red = XT;
#pragma unroll
  for (int r = 0; r < 4; ++r) {
    red[w * 1024 + (lb * 4 + r) * 32 + lm]           = p00[r];
    red[w * 1024 + (lb * 4 + r) * 32 + 16 + lm]      = p01[r];
    red[w * 1024 + (16 + lb * 4 + r) * 32 + lm]      = p10[r];
    red[w * 1024 + (16 + lb * 4 + r) * 32 + 16 + lm] = p11[r];
  }
  __syncthreads();
  for (int k = tid; k < 1024; k += 256) {
    const float s = red[k] + red[1024 + k] + red[2048 + k] + red[3072 + k];
    atomicAdd(&ws[OFF_P + b * 1024 + k], s);
  }
  __syncthreads();
#pragma unroll
  for (int r = 0; r < 8; ++r) {
    const int ch = (r < 4) ? lb * 4 + r : 16 + lb * 4 + (r - 4);
    red[w * 1024 + ch * 32 + lm]      = cs0[r];
    red[w * 1024 + ch * 32 + 16 + lm] = cs1[r];
  }
  __syncthreads();
  for (int k = tid; k < 1024; k += 256) {
    const float s = red[k] + red[1024 + k] + red[2048 + k] + red[3072 + k];
    atomicAdd(&ws[OFF_CS + b * 1024 + k], s);
  }
}

// Pass 2: softmax prologue (block coop), then wave-private dbuf 32-pos tiles,
// counted vmcnt, no loop barriers. V = Wv*X, T = A^T V, out = x(LDS) + gamma*T.
__global__ __launch_bounds__(256) void pass2_kernel(
    const float* __restrict__ x, const float* __restrict__ Wq,
    const float* __restrict__ bq, const float* __restrict__ Wk,
    const float* __restrict__ bk, const float* __restrict__ Wv,
    const float* __restrict__ bv, const float* __restrict__ gm,
    const float* __restrict__ ws, float* __restrict__ out) {
  __shared__ __align__(16) float XT[8 * WT2];
  __shared__ float Sm[1024];
  __shared__ float u_l[32], v_l[32], su_l[32], sv_l[32], ca_l[32];
  __shared__ float beta_l;

  const int tid = threadIdx.x;
  const int w = tid >> 6, l = tid & 63, lm = tid & 15, lb = (tid >> 4) & 3;
  const int b = blockIdx.y;
  const size_t xbase = (size_t)b * 32 * MSP;
  const int wbase = (blockIdx.x * 4 + w) * (NT * 32);

  const int srow = l >> 3;
  const int scol = (((l & 7) + srow) & 7) * 4;
  float* wbuf0 = XT + (w * 2 + 0) * WT2;
  float* wbuf1 = XT + (w * 2 + 1) * WT2;
  const float* csrc[4];
#pragma unroll
  for (int c = 0; c < 4; ++c)
    csrc[c] = x + xbase + (size_t)(c * 8 + srow) * MSP + scol;

  // issue tile0 (completes under softmax prologue)
#pragma unroll
  for (int c = 0; c < 4; ++c)
    GLDS16(csrc[c] + wbase, wbuf0 + c * CSF2);

  // ---- per-block softmax prologue ----
  if (tid < 32) {
    float u = 0.f;
#pragma unroll
    for (int ch = 0; ch < 32; ++ch) u = fmaf(Wq[ch * 32 + tid], bk[ch], u);
    u_l[tid] = u;
  } else if (tid < 64) {
    const int j = tid - 32;
    float v = 0.f;
#pragma unroll
    for (int ch = 0; ch < 32; ++ch) v = fmaf(bq[ch], Wk[ch * 32 + j], v);
    v_l[j] = v;
  } else if (tid == 64) {
    float bt = 0.f;
#pragma unroll
    for (int ch = 0; ch < 32; ++ch) bt = fmaf(bq[ch], bk[ch], bt);
    beta_l = bt;
  }
  __syncthreads();
  if (tid < 32) {
    float s = 0.f;
#pragma unroll
    for (int a = 0; a < 32; ++a)
      s = fmaf(u_l[a], ws[OFF_CS + b * 1024 + a * 32 + tid], s);
    su_l[tid] = s;
  } else if (tid < 64) {
    const int j = tid - 32;
    float s = 0.f;
#pragma unroll
    for (int a = 0; a < 32; ++a)
      s = fmaf(v_l[a], ws[OFF_CS + b * 1024 + a * 32 + j], s);
    sv_l[j] = s;
  }
  __syncthreads();
  {
    const int si = tid >> 3, sj0 = (tid & 7) * 4;
    float s4[4];
#pragma unroll
    for (int c = 0; c < 4; ++c)
      s4[c] = ws[OFF_P + b * 1024 + si * 32 + sj0 + c] + su_l[si] +
              sv_l[sj0 + c] + 8192.0f * beta_l;
    float mx = fmaxf(fmaxf(s4[0], s4[1]), fmaxf(s4[2], s4[3]));
    mx = fmaxf(mx, __shfl_xor(mx, 1, 8));
    mx = fmaxf(mx, __shfl_xor(mx, 2, 8));
    mx = fmaxf(mx, __shfl_xor(mx, 4, 8));
    float e4[4], sum = 0.f;
#pragma unroll
    for (int c = 0; c < 4; ++c) { e4[c] = expf(s4[c] - mx); sum += e4[c]; }
    sum += __shfl_xor(sum, 1, 8);
    sum += __shfl_xor(sum, 2, 8);
    sum += __shfl_xor(sum, 4, 8);
    const float inv = 1.0f / sum;
#pragma unroll
    for (int c = 0; c < 4; ++c) Sm[si * 32 + sj0 + c] = e4[c] * inv;
  }
  __syncthreads();
  if (tid < 32) {
    float c = 0.f;
#pragma unroll
    for (int ii = 0; ii < 32; ++ii) c += Sm[ii * 32 + tid];
    ca_l[tid] = c;
  }
  // per-lane A-frags and Wv-frags
  bf16x8 a0, a1, wv0, wv1;
#pragma unroll
  for (int r = 0; r < 8; ++r) {
    const int kk = (r < 4) ? lb * 4 + r : 16 + lb * 4 + (r - 4);
    a0[r]  = (short)f2bf(Sm[kk * 32 + lm]);          // A[m=j][k=i], mt=0
    a1[r]  = (short)f2bf(Sm[kk * 32 + 16 + lm]);     // mt=1
    wv0[r] = (short)f2bf(Wv[lm * 32 + kk]);          // B[k=cin][n=ch], ct=0
    wv1[r] = (short)f2bf(Wv[(16 + lm) * 32 + kk]);   // ct=1
  }
  __syncthreads();   // ca_l ready; last barrier (drains tile0 loads too)

  const float gamma = gm[0];
  const float bv0 = bv[lm], bv1 = bv[16 + lm];
  float i00[4], i01[4], i10[4], i11[4];   // acc init = bv[ch] * ca[j]
#pragma unroll
  for (int r = 0; r < 4; ++r) {
    const float c0 = ca_l[lb * 4 + r];
    const float c1 = ca_l[16 + lb * 4 + r];
    i00[r] = bv0 * c0; i01[r] = bv1 * c0;
    i10[r] = bv0 * c1; i11[r] = bv1 * c1;
  }

  int off0[8], off1[8];
#pragma unroll
  for (int r = 0; r < 8; ++r) {
    const int ch = (r < 4) ? lb * 4 + r : 16 + lb * 4 + (r - 4);
    const int base = (ch >> 3) * CSF2 + (ch & 7) * 32 + (lm & 3);
    const int g0 = ((lm >> 2) - (ch & 7)) & 7;
    off0[r] = base + g0 * 4;
    off1[r] = base + ((g0 + 4) & 7) * 4;
  }
  // residual b128: (ch = CT*16+lm, cols MT*16+lb*4 .. +3)
  int res[2][2];
#pragma unroll
  for (int CT = 0; CT < 2; ++CT)
#pragma unroll
    for (int MT = 0; MT < 2; ++MT)
      res[CT][MT] = (CT * 2 + (lm >> 3)) * CSF2 + (lm & 7) * 32 +
                    4 * ((MT * 4 + lb - (lm & 7)) & 7);

#pragma unroll 1
  for (int t = 0; t < NT; ++t) {
    const float* XB = (t & 1) ? wbuf1 : wbuf0;
    float* XN = (t & 1) ? wbuf0 : wbuf1;
    if (t + 1 < NT) {
      const int posn = wbase + (t + 1) * 32;
#pragma unroll
      for (int c = 0; c < 4; ++c)
        GLDS16(csrc[c] + posn, XN + c * CSF2);
      // outstanding: L(t) 4 (oldest) + S(t-1) 4 + L(t+1) 4 -> wait L(t) done
      asm volatile("s_waitcnt vmcnt(8)" ::: "memory");
    } else {
      asm volatile("s_waitcnt vmcnt(4)" ::: "memory");   // L(t) done; S pending
    }
    __builtin_amdgcn_sched_barrier(0);
    const int post = wbase + t * 32;

    bf16x8 xh0, xh1;
#pragma unroll
    for (int r = 0; r < 8; ++r) {
      xh0[r] = (short)f2bf(XB[off0[r]]);
      xh1[r] = (short)f2bf(XB[off1[r]]);
    }
    __builtin_amdgcn_s_setprio(1);
    // chmix transposed: D[m=pos][n=ch]
    f32x4 v00 = {0,0,0,0}, v01 = {0,0,0,0}, v10 = {0,0,0,0}, v11 = {0,0,0,0};
    v00 = MFMA(xh0, wv0, v00); v01 = MFMA(xh0, wv1, v01);
    v10 = MFMA(xh1, wv0, v10); v11 = MFMA(xh1, wv1, v11);

    bf16x8 vb0, vb1;
#pragma unroll
    for (int r = 0; r < 4; ++r) { vb0[r] = (short)f2bf(v00[r]); vb1[r] = (short)f2bf(v01[r]); }
#pragma unroll
    for (int r = 4; r < 8; ++r) { vb0[r] = (short)f2bf(v10[r - 4]); vb1[r] = (short)f2bf(v11[r - 4]); }

    // groupmix: D[m=j][n=ch] (+ bv*ca init)
    f32x4 t00 = {i00[0], i00[1], i00[2], i00[3]};
    f32x4 t01 = {i01[0], i01[1], i01[2], i01[3]};
    f32x4 t10 = {i10[0], i10[1], i10[2], i10[3]};
    f32x4 t11 = {i11[0], i11[1], i11[2], i11[3]};
    t00 = MFMA(a0, vb0, t00); t01 = MFMA(a0, vb1, t01);
    t10 = MFMA(a1, vb0, t10); t11 = MFMA(a1, vb1, t11);
    __builtin_amdgcn_s_setprio(0);

    // epilogue: residual x from LDS tile (fp32 exact); coalesced b128 store
#define EPI(TT, MT, CT)                                                           \
    {                                                                             \
      const f32x4 xr = *reinterpret_cast<const f32x4*>(&XB[res[CT][MT]]);         \
      const size_t addr = xbase + (size_t)((CT) * 16 + lm) * MSP +                \
                          (size_t)(post + (MT) * 16 + lb * 4);                    \
      f32x4 o;                                                                    \
      o[0] = fmaf(gamma, TT[0], xr[0]); o[1] = fmaf(gamma, TT[1], xr[1]);         \
      o[2] = fmaf(gamma, TT[2], xr[2]); o[3] = fmaf(gamma, TT[3], xr[3]);         \
      *reinterpret_cast<f32x4*>(out + addr) = o;                                  \
    }
    EPI(t00, 0, 0); EPI(t01, 0, 1); EPI(t10, 1, 0); EPI(t11, 1, 1);
#undef EPI
  }
}

extern "C" void kernel_launch(void* const* d_in, const int* in_sizes, int n_in,
                              void* d_out, int out_size, void* d_ws, size_t ws_size,
                              hipStream_t stream) {
  const float* x  = (const float*)d_in[0];
  const float* Wq = (const float*)d_in[1];
  const float* bq = (const float*)d_in[2];
  const float* Wk = (const float*)d_in[3];
  const float* bk = (const float*)d_in[4];
  const float* Wv = (const float*)d_in[5];
  const float* bv = (const float*)d_in[6];
  const float* gm = (const float*)d_in[7];
  float* out = (float*)d_out;
  float* ws  = (float*)d_ws;

  hipMemsetAsync(ws, 0, 8192 * sizeof(float), stream);   // zero P + CS
  pass1_kernel<<<dim3(NBLK, BATCH), 256, 0, stream>>>(x, Wq, Wk, ws);
  pass2_kernel<<<dim3(NBLK, BATCH), 256, 0, stream>>>(x, Wq, bq, Wk, bk, Wv, bv,
                                                      gm, ws, out);
}

// Round 9
// 82.019 us; speedup vs baseline: 1.0919x; 1.0919x over previous
//
#include <hip/hip_runtime.h>

typedef __attribute__((ext_vector_type(8))) short bf16x8;
typedef __attribute__((ext_vector_type(4))) float f32x4;

#define MSP   262144          // 64*64*64 spatial per (b, ch)
#define BATCH 4
#define NT    8               // tiles per wave (64 positions each)
#define NBLK  128             // blocks per batch: 128*4 waves*8 tiles*64 pos = MSP

#define CSF   264             // LDS chunk stride in floats (4 rows x 64 + 8 pad)
#define WTILE (8 * CSF)       // floats per wave tile buffer (2112)

// ws layout (float offsets): P[4][1024] then CS[4][1024]
#define OFF_P  0
#define OFF_CS 4096

// async global->LDS, 16B per lane; LDS dest wave-uniform, global src per-lane
#define GLDS16(gsrc, ldst)                                               \
  __builtin_amdgcn_global_load_lds(                                      \
      (const __attribute__((address_space(1))) unsigned int*)(gsrc),     \
      (__attribute__((address_space(3))) unsigned int*)(ldst), 16, 0, 0)

__device__ __forceinline__ unsigned short f2bf(float f) {  // RNE
  unsigned int u = __float_as_uint(f);
  u += 0x7fffu + ((u >> 16) & 1u);
  return (unsigned short)(u >> 16);
}
// hi = RNE bf16, lo = trunc bf16 of residual (pair captures f to ~2^-17 rel)
__device__ __forceinline__ void split2(float f, short* hi, short* lo) {
  unsigned int u = __float_as_uint(f);
  unsigned int uh = u + (0x7fffu + ((u >> 16) & 1u));
  *hi = (short)(uh >> 16);
  const float r = f - __uint_as_float(uh & 0xffff0000u);
  *lo = (short)(__float_as_uint(r) >> 16);
}

#define MFMA(A, B, C) __builtin_amdgcn_mfma_f32_16x16x32_bf16(A, B, C, 0, 0, 0)

// k-hat mapping: reg r<4 -> ch = 4*lb+r, r>=4 -> 16+4*lb+(r-4).
// Used consistently for BOTH operands of every MFMA => any true HW k-order cancels.
// LDS tile layout (per wave): chunk c holds rows 4c..4c+3, 64 floats each:
//   elem(ch, col) at  (ch>>2)*CSF + (ch&3)*64 + col      (CSF=264 spreads banks)

// Pass 1: wave-private double-buffered tiles, counted-vmcnt pipeline, NO loop
// barriers. Y = U*X (MFMA), P += X^T Y (MFMA), colsum fp32; atomic P/CS.
__global__ __launch_bounds__(256) void pass1_kernel(
    const float* __restrict__ x, const float* __restrict__ Wq,
    const float* __restrict__ Wk, float* __restrict__ ws) {
  __shared__ float XT[8 * WTILE];   // 4 waves x 2 bufs x 2112 floats (~66 KB)
  __shared__ float UW[3072];        // WqL | WkL | UL
  const int tid = threadIdx.x;
  const int w = tid >> 6, l = tid & 63, lm = tid & 15, lb = (tid >> 4) & 3;
  const int b = blockIdx.y;
  const size_t xbase = (size_t)b * 32 * MSP;
  const int wbase = (blockIdx.x * 4 + w) * (NT * 64);   // wave's position range

  const int srow = l >> 4;          // staging: row within chunk
  const int scol = (l & 15) * 4;    // staging: col (floats)
  float* wbuf0 = XT + (w * 2 + 0) * WTILE;
  float* wbuf1 = XT + (w * 2 + 1) * WTILE;

  // issue tile0 (completes under the U-prep barriers below)
#pragma unroll
  for (int c = 0; c < 8; ++c)
    GLDS16(x + xbase + (size_t)(c * 4 + srow) * MSP + wbase + scol,
           wbuf0 + c * CSF);

  // ---- per-block U prep ----
  {
    float* WqL = UW;
    float* WkL = UW + 1024;
    for (int k = tid; k < 1024; k += 256) { WqL[k] = Wq[k]; WkL[k] = Wk[k]; }
    __syncthreads();
    float* UL = UW + 2048;   // row-major U[aa][bb]
    for (int k = tid; k < 1024; k += 256) {
      const int aa = k >> 5, bb = k & 31;
      float s = 0.f;
#pragma unroll
      for (int ch = 0; ch < 32; ++ch)
        s = fmaf(WqL[ch * 32 + aa], WkL[ch * 32 + bb], s);
      UL[k] = s;
    }
    __syncthreads();
  }
  bf16x8 uh0, ul0, uh1, ul1;
  {
    const float* UL = UW + 2048;
#pragma unroll
    for (int r = 0; r < 8; ++r) {
      const int kk = (r < 4) ? lb * 4 + r : 16 + lb * 4 + (r - 4);
      short h, lo;
      split2(UL[lm * 32 + kk], &h, &lo);        uh0[r] = h; ul0[r] = lo;
      split2(UL[(16 + lm) * 32 + kk], &h, &lo); uh1[r] = h; ul1[r] = lo;
    }
  }

  int ldsoff[8];
#pragma unroll
  for (int r = 0; r < 8; ++r) {
    const int ch = (r < 4) ? lb * 4 + r : 16 + lb * 4 + (r - 4);
    ldsoff[r] = (ch >> 2) * CSF + (ch & 3) * 64 + lm;
  }

  f32x4 p00 = {0, 0, 0, 0}, p01 = {0, 0, 0, 0}, p10 = {0, 0, 0, 0}, p11 = {0, 0, 0, 0};
  float cs0[8], cs1[8];
#pragma unroll
  for (int r = 0; r < 8; ++r) { cs0[r] = 0.f; cs1[r] = 0.f; }

#pragma unroll 1
  for (int t = 0; t < NT; ++t) {
    const float* XB = (t & 1) ? wbuf1 : wbuf0;
    float* XN = (t & 1) ? wbuf0 : wbuf1;
    if (t + 1 < NT) {   // prefetch next tile into other buffer, counted wait
      const int posn = wbase + (t + 1) * 64;
#pragma unroll
      for (int c = 0; c < 8; ++c)
        GLDS16(x + xbase + (size_t)(c * 4 + srow) * MSP + posn + scol,
               XN + c * CSF);
      asm volatile("s_waitcnt vmcnt(8)" ::: "memory");   // tile t ready
    } else {
      asm volatile("s_waitcnt vmcnt(0)" ::: "memory");
    }
    __builtin_amdgcn_sched_barrier(0);

#pragma unroll
    for (int g2 = 0; g2 < 2; ++g2) {
      const int pl = g2 * 32;
      float xf0[8], xf1[8];
#pragma unroll
      for (int r = 0; r < 8; ++r) {
        xf0[r] = XB[ldsoff[r] + pl];
        xf1[r] = XB[ldsoff[r] + pl + 16];
      }
      bf16x8 xh0, xl0, xh1, xl1;
#pragma unroll
      for (int r = 0; r < 8; ++r) {
        short h, lo;
        split2(xf0[r], &h, &lo); xh0[r] = h; xl0[r] = lo;
        split2(xf1[r], &h, &lo); xh1[r] = h; xl1[r] = lo;
        cs0[r] += xf0[r];  cs1[r] += xf1[r];
      }

      // channel mix: Y[ch][pos]; hh + hl + lh
      f32x4 y00 = {0,0,0,0}, y01 = {0,0,0,0}, y10 = {0,0,0,0}, y11 = {0,0,0,0};
      y00 = MFMA(uh0, xh0, y00); y00 = MFMA(uh0, xl0, y00); y00 = MFMA(ul0, xh0, y00);
      y01 = MFMA(uh1, xh0, y01); y01 = MFMA(uh1, xl0, y01); y01 = MFMA(ul1, xh0, y01);
      y10 = MFMA(uh0, xh1, y10); y10 = MFMA(uh0, xl1, y10); y10 = MFMA(ul0, xh1, y10);
      y11 = MFMA(uh1, xh1, y11); y11 = MFMA(uh1, xl1, y11); y11 = MFMA(ul1, xh1, y11);

      // repack Y accs into k-hat B-frags + split
      bf16x8 yh0, yl0, yh1, yl1;
#pragma unroll
      for (int r = 0; r < 4; ++r) {
        short h, lo;
        split2(y00[r], &h, &lo); yh0[r] = h; yl0[r] = lo;
        split2(y10[r], &h, &lo); yh1[r] = h; yl1[r] = lo;
      }
#pragma unroll
      for (int r = 4; r < 8; ++r) {
        short h, lo;
        split2(y01[r - 4], &h, &lo); yh0[r] = h; yl0[r] = lo;
        split2(y11[r - 4], &h, &lo); yh1[r] = h; yl1[r] = lo;
      }

      // Gram: P[it][jt] += X^T Y; hh + hl + lh
      p00 = MFMA(xh0, yh0, p00); p00 = MFMA(xh0, yl0, p00); p00 = MFMA(xl0, yh0, p00);
      p01 = MFMA(xh0, yh1, p01); p01 = MFMA(xh0, yl1, p01); p01 = MFMA(xl0, yh1, p01);
      p10 = MFMA(xh1, yh0, p10); p10 = MFMA(xh1, yl0, p10); p10 = MFMA(xl1, yh0, p10);
      p11 = MFMA(xh1, yh1, p11); p11 = MFMA(xh1, yl1, p11); p11 = MFMA(xl1, yh1, p11);
    }
  }

  // block reduce (reuse XT as [4][1024] scratch) — barriers only here
  __syncthreads();
  float* red = XT;
#pragma unroll
  for (int r = 0; r < 4; ++r) {
    red[w * 1024 + (lb * 4 + r) * 32 + lm]           = p00[r];
    red[w * 1024 + (lb * 4 + r) * 32 + 16 + lm]      = p01[r];
    red[w * 1024 + (16 + lb * 4 + r) * 32 + lm]      = p10[r];
    red[w * 1024 + (16 + lb * 4 + r) * 32 + 16 + lm] = p11[r];
  }
  __syncthreads();
  for (int k = tid; k < 1024; k += 256) {
    const float s = red[k] + red[1024 + k] + red[2048 + k] + red[3072 + k];
    atomicAdd(&ws[OFF_P + b * 1024 + k], s);
  }
  __syncthreads();
#pragma unroll
  for (int r = 0; r < 8; ++r) {
    const int ch = (r < 4) ? lb * 4 + r : 16 + lb * 4 + (r - 4);
    red[w * 1024 + ch * 32 + lm]      = cs0[r];
    red[w * 1024 + ch * 32 + 16 + lm] = cs1[r];
  }
  __syncthreads();
  for (int k = tid; k < 1024; k += 256) {
    const float s = red[k] + red[1024 + k] + red[2048 + k] + red[3072 + k];
    atomicAdd(&ws[OFF_CS + b * 1024 + k], s);
  }
}

// Pass 2: softmax prologue (block coop), then wave-private dbuf tiles with
// counted vmcnt — no loop barriers. V = Wv*X, T = A^T V.
// NEW: o = x + gamma*T is written back into the LDS tile in place, then stored
// with the staging-inverse mapping -> each store = 4 x 256B contiguous segments
// (was 16 x 64B). Block order reversed so pass2 starts on L3-hot tail of x.
__global__ __launch_bounds__(256) void pass2_kernel(
    const float* __restrict__ x, const float* __restrict__ Wq,
    const float* __restrict__ bq, const float* __restrict__ Wk,
    const float* __restrict__ bk, const float* __restrict__ Wv,
    const float* __restrict__ bv, const float* __restrict__ gm,
    const float* __restrict__ ws, float* __restrict__ out) {
  __shared__ float XT[8 * WTILE];
  __shared__ float Sm[1024];
  __shared__ float u_l[32], v_l[32], su_l[32], sv_l[32], ca_l[32];
  __shared__ float beta_l;

  const int tid = threadIdx.x;
  const int w = tid >> 6, l = tid & 63, lm = tid & 15, lb = (tid >> 4) & 3;
  const int b = blockIdx.y;
  const size_t xbase = (size_t)b * 32 * MSP;
  const int wbase = ((NBLK - 1 - blockIdx.x) * 4 + w) * (NT * 64);  // reversed

  const int srow = l >> 4;
  const int scol = (l & 15) * 4;
  float* wbuf0 = XT + (w * 2 + 0) * WTILE;
  float* wbuf1 = XT + (w * 2 + 1) * WTILE;

  // issue tile0 (completes under softmax prologue barriers)
#pragma unroll
  for (int c = 0; c < 8; ++c)
    GLDS16(x + xbase + (size_t)(c * 4 + srow) * MSP + wbase + scol,
           wbuf0 + c * CSF);

  // ---- per-block softmax prologue ----
  if (tid < 32) {
    float u = 0.f;
#pragma unroll
    for (int ch = 0; ch < 32; ++ch) u = fmaf(Wq[ch * 32 + tid], bk[ch], u);
    u_l[tid] = u;
  } else if (tid < 64) {
    const int j = tid - 32;
    float v = 0.f;
#pragma unroll
    for (int ch = 0; ch < 32; ++ch) v = fmaf(bq[ch], Wk[ch * 32 + j], v);
    v_l[j] = v;
  } else if (tid == 64) {
    float bt = 0.f;
#pragma unroll
    for (int ch = 0; ch < 32; ++ch) bt = fmaf(bq[ch], bk[ch], bt);
    beta_l = bt;
  }
  __syncthreads();
  if (tid < 32) {
    float s = 0.f;
#pragma unroll
    for (int a = 0; a < 32; ++a)
      s = fmaf(u_l[a], ws[OFF_CS + b * 1024 + a * 32 + tid], s);
    su_l[tid] = s;
  } else if (tid < 64) {
    const int j = tid - 32;
    float s = 0.f;
#pragma unroll
    for (int a = 0; a < 32; ++a)
      s = fmaf(v_l[a], ws[OFF_CS + b * 1024 + a * 32 + j], s);
    sv_l[j] = s;
  }
  __syncthreads();
  {
    const int si = tid >> 3, sj0 = (tid & 7) * 4;
    float s4[4];
#pragma unroll
    for (int c = 0; c < 4; ++c)
      s4[c] = ws[OFF_P + b * 1024 + si * 32 + sj0 + c] + su_l[si] +
              sv_l[sj0 + c] + 8192.0f * beta_l;
    float mx = fmaxf(fmaxf(s4[0], s4[1]), fmaxf(s4[2], s4[3]));
    mx = fmaxf(mx, __shfl_xor(mx, 1, 8));
    mx = fmaxf(mx, __shfl_xor(mx, 2, 8));
    mx = fmaxf(mx, __shfl_xor(mx, 4, 8));
    float e4[4], sum = 0.f;
#pragma unroll
    for (int c = 0; c < 4; ++c) { e4[c] = expf(s4[c] - mx); sum += e4[c]; }
    sum += __shfl_xor(sum, 1, 8);
    sum += __shfl_xor(sum, 2, 8);
    sum += __shfl_xor(sum, 4, 8);
    const float inv = 1.0f / sum;
#pragma unroll
    for (int c = 0; c < 4; ++c) Sm[si * 32 + sj0 + c] = e4[c] * inv;
  }
  __syncthreads();
  if (tid < 32) {
    float c = 0.f;
#pragma unroll
    for (int ii = 0; ii < 32; ++ii) c += Sm[ii * 32 + tid];
    ca_l[tid] = c;
  }
  // per-lane A-frags and Wv-frags
  bf16x8 a0, a1, wv0, wv1;
#pragma unroll
  for (int r = 0; r < 8; ++r) {
    const int kk = (r < 4) ? lb * 4 + r : 16 + lb * 4 + (r - 4);
    a0[r]  = (short)f2bf(Sm[kk * 32 + lm]);          // A[m=j][k=i], mt=0
    a1[r]  = (short)f2bf(Sm[kk * 32 + 16 + lm]);     // mt=1
    wv0[r] = (short)f2bf(Wv[lm * 32 + kk]);          // B[k=cin][n=ch], ct=0
    wv1[r] = (short)f2bf(Wv[(16 + lm) * 32 + kk]);   // ct=1
  }
  __syncthreads();   // ca_l ready; last barrier (drains tile0 loads too)

  const float gamma = gm[0];
  const float bv0 = bv[lm], bv1 = bv[16 + lm];
  float i00[4], i01[4], i10[4], i11[4];   // acc init = bv[ch] * ca[j]
#pragma unroll
  for (int r = 0; r < 4; ++r) {
    const float c0 = ca_l[lb * 4 + r];
    const float c1 = ca_l[16 + lb * 4 + r];
    i00[r] = bv0 * c0; i01[r] = bv1 * c0;
    i10[r] = bv0 * c1; i11[r] = bv1 * c1;
  }

  int ldsoff[8];
#pragma unroll
  for (int r = 0; r < 8; ++r) {
    const int ch = (r < 4) ? lb * 4 + r : 16 + lb * 4 + (r - 4);
    ldsoff[r] = (ch >> 2) * CSF + (ch & 3) * 64 + lm;
  }
  // residual/o element (ch = CT*16+lm, cols MT*16+lb*4 .. +3)
  int resoff[2][2];
#pragma unroll
  for (int CT = 0; CT < 2; ++CT)
#pragma unroll
    for (int MT = 0; MT < 2; ++MT)
      resoff[CT][MT] = (CT * 4 + (lm >> 2)) * CSF + (lm & 3) * 64 +
                       MT * 16 + lb * 4;

#pragma unroll 1
  for (int t = 0; t < NT; ++t) {
    float* XB = (t & 1) ? wbuf1 : wbuf0;
    float* XN = (t & 1) ? wbuf0 : wbuf1;
    if (t + 1 < NT) {
      const int posn = wbase + (t + 1) * 64;
#pragma unroll
      for (int c = 0; c < 8; ++c)
        GLDS16(x + xbase + (size_t)(c * 4 + srow) * MSP + posn + scol,
               XN + c * CSF);
      if (t == 0)
        asm volatile("s_waitcnt vmcnt(8)" ::: "memory");    // only L1 pending
      else
        asm volatile("s_waitcnt vmcnt(16)" ::: "memory");   // L(t) drained; S(t-1)+L(t+1) pending
    } else {
      asm volatile("s_waitcnt vmcnt(8)" ::: "memory");      // L(t) drained; S(t-1) pending
    }
    __builtin_amdgcn_sched_barrier(0);
    const int post = wbase + t * 64;

#pragma unroll
    for (int g2 = 0; g2 < 2; ++g2) {
      const int pl = g2 * 32;
      bf16x8 xh0, xh1;
#pragma unroll
      for (int r = 0; r < 8; ++r) {
        xh0[r] = (short)f2bf(XB[ldsoff[r] + pl]);
        xh1[r] = (short)f2bf(XB[ldsoff[r] + pl + 16]);
      }
      // chmix transposed: D[m=pos][n=ch]
      f32x4 v00 = {0,0,0,0}, v01 = {0,0,0,0}, v10 = {0,0,0,0}, v11 = {0,0,0,0};
      v00 = MFMA(xh0, wv0, v00); v01 = MFMA(xh0, wv1, v01);
      v10 = MFMA(xh1, wv0, v10); v11 = MFMA(xh1, wv1, v11);

      bf16x8 vb0, vb1;
#pragma unroll
      for (int r = 0; r < 4; ++r) { vb0[r] = (short)f2bf(v00[r]); vb1[r] = (short)f2bf(v01[r]); }
#pragma unroll
      for (int r = 4; r < 8; ++r) { vb0[r] = (short)f2bf(v10[r - 4]); vb1[r] = (short)f2bf(v11[r - 4]); }

      // groupmix: D[m=j][n=ch] (+ bv*ca init)
      f32x4 t00 = {i00[0], i00[1], i00[2], i00[3]};
      f32x4 t01 = {i01[0], i01[1], i01[2], i01[3]};
      f32x4 t10 = {i10[0], i10[1], i10[2], i10[3]};
      f32x4 t11 = {i11[0], i11[1], i11[2], i11[3]};
      t00 = MFMA(a0, vb0, t00); t01 = MFMA(a0, vb1, t01);
      t10 = MFMA(a1, vb0, t10); t11 = MFMA(a1, vb1, t11);

      // o = x + gamma*T written back IN PLACE into the LDS tile (same lane
      // reads then writes the same element; later frag reads use disjoint cols)
#define EPI(TT, MT, CT)                                                           \
      {                                                                           \
        float* p = &XB[resoff[CT][MT] + pl];                                      \
        const f32x4 xr = *reinterpret_cast<const f32x4*>(p);                      \
        f32x4 o;                                                                  \
        o[0] = fmaf(gamma, TT[0], xr[0]); o[1] = fmaf(gamma, TT[1], xr[1]);       \
        o[2] = fmaf(gamma, TT[2], xr[2]); o[3] = fmaf(gamma, TT[3], xr[3]);       \
        *reinterpret_cast<f32x4*>(p) = o;                                         \
      }
      EPI(t00, 0, 0); EPI(t01, 0, 1); EPI(t10, 1, 0); EPI(t11, 1, 1);
#undef EPI
    }

    // store phase: staging-inverse mapping -> 4 x 256B contiguous per instr
#pragma unroll
    for (int c = 0; c < 8; ++c) {
      const f32x4 o4 =
          *reinterpret_cast<const f32x4*>(&XB[c * CSF + srow * 64 + scol]);
      *reinterpret_cast<f32x4*>(
          out + xbase + (size_t)(c * 4 + srow) * MSP + post + scol) = o4;
    }
  }
}

extern "C" void kernel_launch(void* const* d_in, const int* in_sizes, int n_in,
                              void* d_out, int out_size, void* d_ws, size_t ws_size,
                              hipStream_t stream) {
  const float* x  = (const float*)d_in[0];
  const float* Wq = (const float*)d_in[1];
  const float* bq = (const float*)d_in[2];
  const float* Wk = (const float*)d_in[3];
  const float* bk = (const float*)d_in[4];
  const float* Wv = (const float*)d_in[5];
  const float* bv = (const float*)d_in[6];
  const float* gm = (const float*)d_in[7];
  float* out = (float*)d_out;
  float* ws  = (float*)d_ws;

  hipMemsetAsync(ws, 0, 8192 * sizeof(float), stream);   // zero P + CS
  pass1_kernel<<<dim3(NBLK, BATCH), 256, 0, stream>>>(x, Wq, Wk, ws);
  pass2_kernel<<<dim3(NBLK, BATCH), 256, 0, stream>>>(x, Wq, bq, Wk, bk, Wv, bv,
                                                      gm, ws, out);
}